// Round 5
// baseline (509.563 us; speedup 1.0000x reference)
//
#include <hip/hip_runtime.h>
#include <cstdint>
#include <cstdlib>
#include <cstring>
#include <vector>

#define RW_VOCAB 512
#define RW_T 64
#define RW_D 32
#define RW_NNODES 4000
#define RW_NIN 2048      // T*D
#define RW_NBIAS 2
#define RW_BATCH 512
#define RW_NLAYERS 6
#define RW_THREADS 512

// ---------------------------------------------------------------------------
// Host-side replication of np.random.RandomState(0) graph construction.
// (verified: round-3 passed with absmax 1.2e-4.)
// Edges kept in numpy generation order (src-major per layer), so the k-th
// edge of layer l has weight index w0_l + k -> the device reads w[] directly,
// contiguously, with no gather and no widx upload.
// ---------------------------------------------------------------------------
namespace {

struct MT19937 {
  uint32_t mt[624];
  int mti;
  void seed(uint32_t s) {
    for (int i = 0; i < 624; ++i) {
      mt[i] = s;
      s = 1812433253u * (s ^ (s >> 30)) + (uint32_t)i + 1u;
    }
    mti = 624;
  }
  inline uint32_t next() {
    if (mti >= 624) {
      for (int i = 0; i < 624; ++i) {
        uint32_t y = (mt[i] & 0x80000000u) | (mt[(i + 1) % 624] & 0x7fffffffu);
        mt[i] = mt[(i + 397) % 624] ^ (y >> 1) ^ ((y & 1u) ? 2567483615u : 0u);
      }
      mti = 0;
    }
    uint32_t y = mt[mti++];
    y ^= y >> 11;
    y ^= (y << 7) & 2636928640u;
    y ^= (y << 15) & 4022730752u;
    y ^= y >> 18;
    return y;
  }
  inline double rnd() {
    uint32_t a = next() >> 5, b = next() >> 6;
    return ((double)a * 67108864.0 + (double)b) / 9007199254740992.0;
  }
};

const int LAYER_SIZES[RW_NLAYERS] = {288, 288, 288, 287, 287, 512};

struct HostGraph {
  int Epad;                 // total padded edges (multiple of 4)
  int p0[RW_NLAYERS];       // padded segment start per layer
  int ep[RW_NLAYERS];       // padded count per layer (multiple of 4)
  int er[RW_NLAYERS];       // real edge count per layer
  int w0[RW_NLAYERS];       // global weight index at layer start
  uint32_t* h_pack;         // pinned: (dst_local<<12)|src_global, dummies = 0
};

HostGraph* build_host_graph() {
  auto* G = new HostGraph();
  MT19937 mt;
  mt.seed(0);
  std::vector<uint32_t> pack;
  pack.reserve(180000);
  int start = RW_NIN + RW_NBIAS;  // 2050
  int wcum = 0;
  for (int li = 0; li < RW_NLAYERS; ++li) {
    const int size = LAYER_SIZES[li];
    G->p0[li] = (int)pack.size();
    G->w0[li] = wcum;
    int cnt = 0;
    for (int u = 0; u < start; ++u) {      // src-major == numpy nonzero order
      for (int v = 0; v < size; ++v) {
        if (mt.rnd() < 0.03) {
          pack.push_back(((uint32_t)v << 12) | (uint32_t)u);
          ++cnt;
        }
      }
    }
    G->er[li] = cnt;
    wcum += cnt;
    while (pack.size() & 3u) pack.push_back(0u);  // dummy: src0,dst0,w=0
    G->ep[li] = (int)pack.size() - G->p0[li];
    start += size;
  }
  G->Epad = (int)pack.size();
  const size_t bytes = (size_t)G->Epad * 4;
  if (hipHostMalloc((void**)&G->h_pack, bytes) != hipSuccess) {
    G->h_pack = (uint32_t*)malloc(bytes);
  }
  memcpy(G->h_pack, pack.data(), bytes);
  return G;
}

}  // namespace

struct LayerArgs {
  int p0[RW_NLAYERS];
  int ep[RW_NLAYERS];
  int er[RW_NLAYERS];
  int w0[RW_NLAYERS];
};

// Build padded weight stream aligned with pack[]: wpad[p0_l + k] = w[w0_l + k]
// for real edges, 0 for dummies (d_ws is poisoned 0xAA -> must write all).
__global__ __launch_bounds__(256) void rwnn_build_w(const float* __restrict__ w,
                                                    float* __restrict__ wpad,
                                                    LayerArgs la, int Epad) {
  const int i = blockIdx.x * blockDim.x + threadIdx.x;
  if (i >= Epad) return;
  int l = 0;
#pragma unroll
  for (int k = 1; k < RW_NLAYERS; ++k)
    if (i >= la.p0[k]) l = k;
  const int kk = i - la.p0[l];
  wpad[i] = (kk < la.er[l]) ? w[la.w0[l] + kk] : 0.0f;
}

// One block per batch row. Edge-parallel within each layer: all threads stream
// the layer's edge list contiguously (coalesced uint4/float4) and scatter via
// LDS atomics into the pre-activation region, which is disjoint from the
// region being read (sources are strictly earlier nodes).
__global__ __launch_bounds__(RW_THREADS) void rwnn_fwd(
    const int* __restrict__ ids, const float* __restrict__ tok,
    const float* __restrict__ pos, const uint32_t* __restrict__ pack,
    const float* __restrict__ wpad, float* __restrict__ out, LayerArgs la) {
  __shared__ float vals[RW_NNODES];
  const int b = blockIdx.x;
  const int tid = threadIdx.x;

  // Embedding: vals[t*32+d] = tok[ids[t]*32+d] + pos[t*32+d]; bias = 1.
  for (int i = tid; i < RW_NIN; i += RW_THREADS) {
    const int t = i >> 5;
    const int d = i & 31;
    const int id = ids[b * RW_T + t];
    vals[i] = tok[(id << 5) + d] + pos[i];
  }
  if (tid < RW_NBIAS) vals[RW_NIN + tid] = 1.0f;

  const int sizes[RW_NLAYERS] = {288, 288, 288, 287, 287, 512};
  int nb = RW_NIN + RW_NBIAS;  // node base of current layer's dsts
  for (int li = 0; li < RW_NLAYERS; ++li) {
    const int size = sizes[li];
    __syncthreads();                                   // prev layer complete
    for (int v = tid; v < size; v += RW_THREADS) vals[nb + v] = 0.0f;
    __syncthreads();                                   // zeros visible

    const int p0 = la.p0[li];
    const int ng = la.ep[li] >> 2;  // groups of 4 edges
    for (int g = tid; g < ng; g += RW_THREADS) {
      const int e = p0 + (g << 2);
      const uint4 pk = *reinterpret_cast<const uint4*>(pack + e);
      const float4 wv = *reinterpret_cast<const float4*>(wpad + e);
      atomicAdd(&vals[nb + (pk.x >> 12)], vals[pk.x & 4095u] * wv.x);
      atomicAdd(&vals[nb + (pk.y >> 12)], vals[pk.y & 4095u] * wv.y);
      atomicAdd(&vals[nb + (pk.z >> 12)], vals[pk.z & 4095u] * wv.z);
      atomicAdd(&vals[nb + (pk.w >> 12)], vals[pk.w & 4095u] * wv.w);
    }
    __syncthreads();                                   // all adds landed

    if (li == RW_NLAYERS - 1) {
      for (int v = tid; v < RW_VOCAB; v += RW_THREADS)
        out[b * RW_VOCAB + v] = vals[nb + v];          // logits: no tanh
    } else {
      for (int v = tid; v < size; v += RW_THREADS)
        vals[nb + v] = tanhf(vals[nb + v]);
    }
    nb += size;
  }
}

// ---------------------------------------------------------------------------
extern "C" void kernel_launch(void* const* d_in, const int* in_sizes, int n_in,
                              void* d_out, int out_size, void* d_ws,
                              size_t ws_size, hipStream_t stream) {
  static HostGraph* G = build_host_graph();  // host-only one-time init

  const int* ids = (const int*)d_in[0];
  const float* tok = (const float*)d_in[1];
  const float* pos = (const float*)d_in[2];
  const float* w = (const float*)d_in[3];
  float* out = (float*)d_out;

  LayerArgs la;
  memcpy(la.p0, G->p0, sizeof(la.p0));
  memcpy(la.ep, G->ep, sizeof(la.ep));
  memcpy(la.er, G->er, sizeof(la.er));
  memcpy(la.w0, G->w0, sizeof(la.w0));

  char* ws = (char*)d_ws;
  uint32_t* d_pack = (uint32_t*)ws;
  float* d_wpad = (float*)(ws + (size_t)G->Epad * 4);

  // Topology upload (d_ws re-poisoned every call -> per-call upload).
  hipMemcpyAsync(d_pack, G->h_pack, (size_t)G->Epad * 4,
                 hipMemcpyHostToDevice, stream);
  rwnn_build_w<<<(G->Epad + 255) / 256, 256, 0, stream>>>(w, d_wpad, la,
                                                          G->Epad);
  rwnn_fwd<<<RW_BATCH, RW_THREADS, 0, stream>>>(ids, tok, pos, d_pack, d_wpad,
                                                out, la);
}

// Round 6
// 171.280 us; speedup vs baseline: 2.9750x; 2.9750x over previous
//
#include <hip/hip_runtime.h>
#include <cstdint>
#include <cstdlib>
#include <cstring>
#include <vector>

#define RW_VOCAB 512
#define RW_T 64
#define RW_D 32
#define RW_NIN 2048
#define RW_NBIAS 2
#define RW_BATCH 512
#define RW_NLAYERS 6
#define RW_VBLD 4096          // Vb leading dim (nodes padded)

typedef __attribute__((ext_vector_type(8))) short short8;  // bf16x8 frag
typedef __attribute__((ext_vector_type(4))) float f32x4;

// ---------------------------------------------------------------------------
// Host-side replication of np.random.RandomState(0) graph construction.
// (verified passing: rounds 3 & 5, absmax 1.2e-4.)
// ---------------------------------------------------------------------------
namespace {

struct MT19937 {
  uint32_t mt[624];
  int mti;
  void seed(uint32_t s) {
    for (int i = 0; i < 624; ++i) {
      mt[i] = s;
      s = 1812433253u * (s ^ (s >> 30)) + (uint32_t)i + 1u;
    }
    mti = 624;
  }
  inline uint32_t next() {
    if (mti >= 624) {
      for (int i = 0; i < 624; ++i) {
        uint32_t y = (mt[i] & 0x80000000u) | (mt[(i + 1) % 624] & 0x7fffffffu);
        mt[i] = mt[(i + 397) % 624] ^ (y >> 1) ^ ((y & 1u) ? 2567483615u : 0u);
      }
      mti = 0;
    }
    uint32_t y = mt[mti++];
    y ^= y >> 11;
    y ^= (y << 7) & 2636928640u;
    y ^= (y << 15) & 4022730752u;
    y ^= y >> 18;
    return y;
  }
  inline double rnd() {
    uint32_t a = next() >> 5, b = next() >> 6;
    return ((double)a * 67108864.0 + (double)b) / 9007199254740992.0;
  }
};

const int LAYER_SIZES[RW_NLAYERS] = {288, 288, 288, 287, 287, 512};
const int LAYER_START[RW_NLAYERS] = {2050, 2338, 2626, 2914, 3201, 3488};
const int LAYER_NPAD[RW_NLAYERS]  = {288, 288, 288, 288, 288, 512};
const int LAYER_NT[RW_NLAYERS]    = {9, 9, 9, 9, 9, 16};   // N tiles of 32

struct GArgsH {
  int p0[RW_NLAYERS], ep[RW_NLAYERS], er[RW_NLAYERS], w0[RW_NLAYERS];
  int kpad[RW_NLAYERS];
  unsigned wofs[RW_NLAYERS];  // layer W^T base offset, in ushort elements
};

struct HostGraph {
  int Epad;
  GArgsH ga;
  unsigned wdt_elems;       // total dense-W^T elements
  uint32_t* h_pack;         // pinned: (dst_local<<12)|src_global
};

HostGraph* build_host_graph() {
  auto* G = new HostGraph();
  MT19937 mt;
  mt.seed(0);
  std::vector<uint32_t> pack;
  pack.reserve(180000);
  int start = RW_NIN + RW_NBIAS;  // 2050
  int wcum = 0;
  for (int li = 0; li < RW_NLAYERS; ++li) {
    const int size = LAYER_SIZES[li];
    G->ga.p0[li] = (int)pack.size();
    G->ga.w0[li] = wcum;
    int cnt = 0;
    for (int u = 0; u < start; ++u) {      // src-major == numpy nonzero order
      for (int v = 0; v < size; ++v) {
        if (mt.rnd() < 0.03) {
          pack.push_back(((uint32_t)v << 12) | (uint32_t)u);
          ++cnt;
        }
      }
    }
    G->ga.er[li] = cnt;
    wcum += cnt;
    while (pack.size() & 3u) pack.push_back(0u);
    G->ga.ep[li] = (int)pack.size() - G->ga.p0[li];
    start += size;
  }
  G->Epad = (int)pack.size();
  unsigned ofs = 0;
  for (int li = 0; li < RW_NLAYERS; ++li) {
    G->ga.kpad[li] = ((LAYER_START[li] + 63) / 64) * 64;  // 2112,2368,2688,2944,3264,3520
    G->ga.wofs[li] = ofs;
    ofs += (unsigned)LAYER_NPAD[li] * (unsigned)G->ga.kpad[li];
  }
  G->wdt_elems = ofs;  // 5,654,528
  const size_t bytes = (size_t)G->Epad * 4;
  if (hipHostMalloc((void**)&G->h_pack, bytes) != hipSuccess)
    G->h_pack = (uint32_t*)malloc(bytes);
  memcpy(G->h_pack, pack.data(), bytes);
  return G;
}

}  // namespace

struct GArgs {
  int p0[RW_NLAYERS], ep[RW_NLAYERS], er[RW_NLAYERS], w0[RW_NLAYERS];
  int kpad[RW_NLAYERS];
  unsigned wofs[RW_NLAYERS];
};

__device__ __forceinline__ unsigned short f2bf(float f) {
  unsigned u = __builtin_bit_cast(unsigned, f);
  return (unsigned short)((u + 0x7fffu + ((u >> 16) & 1u)) >> 16);  // RNE, finite
}

// ---------------------------------------------------------------------------
// init: zero dense W^T, zero pre, build Vb (emb + bias + zero tail)
// ---------------------------------------------------------------------------
__global__ __launch_bounds__(256) void rwnn_init(
    unsigned* __restrict__ wdt32, int nwdt32, float* __restrict__ pre,
    unsigned* __restrict__ vb32, const int* __restrict__ ids,
    const float* __restrict__ tok, const float* __restrict__ pos) {
  const int gt = blockIdx.x * 256 + threadIdx.x;
  const int gs = gridDim.x * 256;
  for (int i = gt; i < nwdt32; i += gs) wdt32[i] = 0u;
  for (int i = gt; i < RW_BATCH * 512; i += gs) pre[i] = 0.0f;
  for (int i = gt; i < RW_BATCH * (RW_VBLD / 2); i += gs) {
    const int b = i >> 11, j = i & 2047;
    const int c0 = j * 2;
    unsigned dw;
    if (c0 >= RW_NIN + RW_NBIAS) {
      dw = 0u;
    } else if (c0 == RW_NIN) {
      dw = 0x3f803f80u;  // two bf16 1.0 bias nodes
    } else {
      const int t = c0 >> 5, d = c0 & 31;
      const int id = ids[b * RW_T + t];
      const float v0 = tok[id * 32 + d] + pos[c0];
      const float v1 = tok[id * 32 + d + 1] + pos[c0 + 1];
      dw = (unsigned)f2bf(v0) | ((unsigned)f2bf(v1) << 16);
    }
    vb32[i] = dw;
  }
}

// scatter sparse weights into dense bf16 W^T[n][k]
__global__ __launch_bounds__(256) void rwnn_scatter(
    const uint32_t* __restrict__ pack, const float* __restrict__ w,
    unsigned short* __restrict__ wdt, GArgs ga, int Epad) {
  const int i = blockIdx.x * 256 + threadIdx.x;
  if (i >= Epad) return;
  int l = 0;
#pragma unroll
  for (int k = 1; k < RW_NLAYERS; ++k)
    if (i >= ga.p0[k]) l = k;
  const int kk = i - ga.p0[l];
  if (kk >= ga.er[l]) return;  // padding slot
  const uint32_t pk = pack[i];
  const unsigned u = pk & 4095u, v = pk >> 12;
  wdt[ga.wofs[l] + (size_t)v * (unsigned)ga.kpad[l] + u] = f2bf(w[ga.w0[l] + kk]);
}

// ---------------------------------------------------------------------------
// GEMM: pre[512, Npad] += Vb[512, K] * W^T[Npad, K]^T   (split-K, fp32 atomics)
// block = 4 waves; block tile 128(M) x 32(N); wave tile 32x32 via 4x 16x16x32
// ---------------------------------------------------------------------------
__global__ __launch_bounds__(256) void rwnn_gemm(
    const unsigned short* __restrict__ Vb, const unsigned short* __restrict__ Bt,
    float* __restrict__ pre, int kpad, int ck) {
  __shared__ unsigned short As[128][32];
  __shared__ unsigned short Bs[32][32];
  const int tid = threadIdx.x;
  const int wave = tid >> 6, lane = tid & 63;
  const int mtile = blockIdx.x, ntile = blockIdx.y;
  const int k0 = blockIdx.z * ck;
  const int k1 = min(k0 + ck, kpad);
  if (k0 >= k1) return;
  f32x4 acc[2][2] = {};
  const int sr = tid >> 2, sc = (tid & 3) * 8;  // staging row / col8
  for (int k = k0; k < k1; k += 32) {
    __syncthreads();
    {  // stage A: 128 rows x 32 cols bf16
      const float4 v0 =
          *(const float4*)(Vb + (size_t)(mtile * 128 + sr) * RW_VBLD + k + sc);
      *(float4*)(&As[sr][sc]) = v0;
      const float4 v1 = *(const float4*)(Vb +
          (size_t)(mtile * 128 + sr + 64) * RW_VBLD + k + sc);
      *(float4*)(&As[sr + 64][sc]) = v1;
    }
    if (tid < 128) {  // stage B^T: 32 n-rows x 32 k-cols
      *(float4*)(&Bs[sr][sc]) =
          *(const float4*)(Bt + (size_t)(ntile * 32 + sr) * kpad + k + sc);
    }
    __syncthreads();
    const int lr = lane & 15, lk = (lane >> 4) * 8;
    const short8 a0 = *(const short8*)(&As[wave * 32 + lr][lk]);
    const short8 a1 = *(const short8*)(&As[wave * 32 + 16 + lr][lk]);
    const short8 b0 = *(const short8*)(&Bs[lr][lk]);
    const short8 b1 = *(const short8*)(&Bs[16 + lr][lk]);
    acc[0][0] = __builtin_amdgcn_mfma_f32_16x16x32_bf16(a0, b0, acc[0][0], 0, 0, 0);
    acc[0][1] = __builtin_amdgcn_mfma_f32_16x16x32_bf16(a0, b1, acc[0][1], 0, 0, 0);
    acc[1][0] = __builtin_amdgcn_mfma_f32_16x16x32_bf16(a1, b0, acc[1][0], 0, 0, 0);
    acc[1][1] = __builtin_amdgcn_mfma_f32_16x16x32_bf16(a1, b1, acc[1][1], 0, 0, 0);
  }
  const int lr = lane & 15, lq = lane >> 4;
#pragma unroll
  for (int ms = 0; ms < 2; ++ms)
#pragma unroll
    for (int ns = 0; ns < 2; ++ns)
#pragma unroll
      for (int r = 0; r < 4; ++r) {
        const int grow = mtile * 128 + wave * 32 + ms * 16 + lq * 4 + r;
        const int gcol = ntile * 32 + ns * 16 + lr;
        atomicAdd(pre + (size_t)grow * 512 + gcol, acc[ms][ns][r]);
      }
}

// per-layer epilogue: tanh(+bf16) into Vb (or fp32 logits into out); re-zero pre
__global__ __launch_bounds__(256) void rwnn_epi(
    float* __restrict__ pre, unsigned short* __restrict__ Vb,
    float* __restrict__ out, int start, int nsize, int last) {
  const int b = blockIdx.x;
  for (int n = threadIdx.x; n < 512; n += 256) {
    const float v = pre[(size_t)b * 512 + n];
    pre[(size_t)b * 512 + n] = 0.0f;
    if (n < nsize) {
      if (last)
        out[(size_t)b * 512 + n] = v;
      else
        Vb[(size_t)b * RW_VBLD + start + n] = f2bf(tanhf(v));
    }
  }
}

// ---------------------------------------------------------------------------
// Fallback (verified round-5 path) if ws_size is too small for the dense plan
// ---------------------------------------------------------------------------
__global__ __launch_bounds__(256) void rwnn_build_w(const float* __restrict__ w,
                                                    float* __restrict__ wpad,
                                                    GArgs ga, int Epad) {
  const int i = blockIdx.x * 256 + threadIdx.x;
  if (i >= Epad) return;
  int l = 0;
#pragma unroll
  for (int k = 1; k < RW_NLAYERS; ++k)
    if (i >= ga.p0[k]) l = k;
  const int kk = i - ga.p0[l];
  wpad[i] = (kk < ga.er[l]) ? w[ga.w0[l] + kk] : 0.0f;
}

__global__ __launch_bounds__(512) void rwnn_fwd_sparse(
    const int* __restrict__ ids, const float* __restrict__ tok,
    const float* __restrict__ pos, const uint32_t* __restrict__ pack,
    const float* __restrict__ wpad, float* __restrict__ out, GArgs ga) {
  __shared__ float vals[4000];
  const int b = blockIdx.x;
  const int tid = threadIdx.x;
  for (int i = tid; i < RW_NIN; i += 512) {
    const int t = i >> 5, d = i & 31;
    vals[i] = tok[(ids[b * RW_T + t] << 5) + d] + pos[i];
  }
  if (tid < RW_NBIAS) vals[RW_NIN + tid] = 1.0f;
  const int sizes[RW_NLAYERS] = {288, 288, 288, 287, 287, 512};
  int nb = RW_NIN + RW_NBIAS;
  for (int li = 0; li < RW_NLAYERS; ++li) {
    const int size = sizes[li];
    __syncthreads();
    for (int v = tid; v < size; v += 512) vals[nb + v] = 0.0f;
    __syncthreads();
    const int p0 = ga.p0[li], ng = ga.ep[li] >> 2;
    for (int g = tid; g < ng; g += 512) {
      const int e = p0 + (g << 2);
      const uint4 pk = *reinterpret_cast<const uint4*>(pack + e);
      const float4 wv = *reinterpret_cast<const float4*>(wpad + e);
      atomicAdd(&vals[nb + (pk.x >> 12)], vals[pk.x & 4095u] * wv.x);
      atomicAdd(&vals[nb + (pk.y >> 12)], vals[pk.y & 4095u] * wv.y);
      atomicAdd(&vals[nb + (pk.z >> 12)], vals[pk.z & 4095u] * wv.z);
      atomicAdd(&vals[nb + (pk.w >> 12)], vals[pk.w & 4095u] * wv.w);
    }
    __syncthreads();
    if (li == RW_NLAYERS - 1) {
      for (int v = tid; v < RW_VOCAB; v += 512) out[b * RW_VOCAB + v] = vals[nb + v];
    } else {
      for (int v = tid; v < size; v += 512) vals[nb + v] = tanhf(vals[nb + v]);
    }
    nb += size;
  }
}

// ---------------------------------------------------------------------------
extern "C" void kernel_launch(void* const* d_in, const int* in_sizes, int n_in,
                              void* d_out, int out_size, void* d_ws,
                              size_t ws_size, hipStream_t stream) {
  static HostGraph* G = build_host_graph();
  const int Epad = G->Epad;

  const int* ids = (const int*)d_in[0];
  const float* tok = (const float*)d_in[1];
  const float* pos = (const float*)d_in[2];
  const float* w = (const float*)d_in[3];
  float* out = (float*)d_out;

  GArgs ga;
  memcpy(&ga, &G->ga, sizeof(GArgs));

  char* ws = (char*)d_ws;
  const size_t packB = ((size_t)Epad * 4 + 255) & ~(size_t)255;
  const size_t wdtB = ((size_t)G->wdt_elems * 2 + 255) & ~(size_t)255;
  const size_t vbB = (size_t)RW_BATCH * RW_VBLD * 2;   // 4 MB
  const size_t preB = (size_t)RW_BATCH * 512 * 4;      // 1 MB
  const size_t need = packB + wdtB + vbB + preB;

  uint32_t* d_pack = (uint32_t*)ws;
  hipMemcpyAsync(d_pack, G->h_pack, (size_t)Epad * 4, hipMemcpyHostToDevice,
                 stream);

  if (ws_size < need) {  // fallback: verified sparse path
    float* d_wpad = (float*)(ws + packB);
    rwnn_build_w<<<(Epad + 255) / 256, 256, 0, stream>>>(w, d_wpad, ga, Epad);
    rwnn_fwd_sparse<<<RW_BATCH, 512, 0, stream>>>(ids, tok, pos, d_pack, d_wpad,
                                                  out, ga);
    return;
  }

  unsigned short* d_wdt = (unsigned short*)(ws + packB);
  unsigned short* d_vb = (unsigned short*)(ws + packB + wdtB);
  float* d_pre = (float*)(ws + packB + wdtB + vbB);

  rwnn_init<<<2048, 256, 0, stream>>>((unsigned*)d_wdt,
                                      (int)(G->wdt_elems / 2), d_pre,
                                      (unsigned*)d_vb, ids, tok, pos);
  rwnn_scatter<<<(Epad + 255) / 256, 256, 0, stream>>>(d_pack, w, d_wdt, ga,
                                                       Epad);
  for (int l = 0; l < RW_NLAYERS; ++l) {
    const int nt = LAYER_NT[l];
    const int SK = (l == RW_NLAYERS - 1) ? 4 : 7;
    const int kpad = ga.kpad[l];
    const int ck = (((kpad + SK - 1) / SK) + 31) & ~31;
    rwnn_gemm<<<dim3(4, nt, SK), 256, 0, stream>>>(
        d_vb, d_wdt + ga.wofs[l], d_pre, kpad, ck);
    rwnn_epi<<<RW_BATCH, 256, 0, stream>>>(d_pre, d_vb, out, LAYER_START[l],
                                           LAYER_SIZES[l],
                                           l == RW_NLAYERS - 1 ? 1 : 0);
  }
}